// Round 13
// baseline (62.307 us; speedup 1.0000x reference)
//
#include <hip/hip_runtime.h>

#define N_ROWS 262144
#define DIM 64
#define NEMB 512

typedef __attribute__((ext_vector_type(4))) float f32x4;

// Prep: w2b = bf8(e5m2) of (-2*w), row-major [512][64] bytes; wsq1 = ||w||^2+1.
// e5m2 because |2w| <= 2^-8 < e4m3's min normal 2^-6; e5m2 min normal 2^-14.
// z uses e4m3 (better mantissa, z~N(0,1)).
__global__ __launch_bounds__(256) void vq_prep(
    const float* __restrict__ w, float* __restrict__ wsq1,
    int* __restrict__ w2b)
{
    int row = blockIdx.x * 256 + threadIdx.x;
    if (row >= NEMB) return;
    const float* wr = w + row * DIM;
    float s = 0.f;
    int packed[16];
#pragma unroll
    for (int d4 = 0; d4 < 16; ++d4) {
        f32x4 v = *(const f32x4*)(wr + d4 * 4);
        s = fmaf(v[0], v[0], fmaf(v[1], v[1], fmaf(v[2], v[2], fmaf(v[3], v[3], s))));
        int p = __builtin_amdgcn_cvt_pk_bf8_f32(-2.f * v[0], -2.f * v[1], 0, false);
        p = __builtin_amdgcn_cvt_pk_bf8_f32(-2.f * v[2], -2.f * v[3], p, true);
        packed[d4] = p;
    }
#pragma unroll
    for (int q = 0; q < 4; ++q)
        ((int4*)w2b)[row * 4 + q] =
            make_int4(packed[q * 4 + 0], packed[q * 4 + 1],
                      packed[q * 4 + 2], packed[q * 4 + 3]);
    wsq1[row] = s + 1.0f;
}

// 8 f32 -> 8 fp8(e4m3) bytes (one i64 B-fragment), accumulating squares.
__device__ inline long cvt_fp8x8(f32x4 a, f32x4 b, float& q) {
    q = fmaf(a[0], a[0], q); q = fmaf(a[1], a[1], q);
    q = fmaf(a[2], a[2], q); q = fmaf(a[3], a[3], q);
    q = fmaf(b[0], b[0], q); q = fmaf(b[1], b[1], q);
    q = fmaf(b[2], b[2], q); q = fmaf(b[3], b[3], q);
    int lo = __builtin_amdgcn_cvt_pk_fp8_f32(a[0], a[1], 0, false);
    lo = __builtin_amdgcn_cvt_pk_fp8_f32(a[2], a[3], lo, true);
    int hi = __builtin_amdgcn_cvt_pk_fp8_f32(b[0], b[1], 0, false);
    hi = __builtin_amdgcn_cvt_pk_fp8_f32(b[2], b[3], hi, true);
    return (long)(unsigned)lo | ((long)hi << 32);
}

// Main: 512 blocks x 512 thr (8 waves) = 2 blocks/CU, 16 waves/CU (proven
// best TLP), fp8 k-loop fully unrolled (R12), PLUS 2-chunk pipeline (R10's
// overlap at full TLP): block owns 512 rows = 2 chunks x 256; wave does 32
// rows/chunk (2 rg). Chunk-1 z loads issue before KLOOP0 (HBM under
// compute); chunk-0 stores drain under cvt1/KLOOP1. k-loop operands all in
// LDS -> lgkm-only. Scores acc = (1+wsq) - 2 z.w via mfma bf8_fp8, C-in =
// wsq1; packed-key argmin; fused gather epilogue.
// C/D layout (m89): m(codeword)=4*(lane>>4)+reg, n(z-row)=lane&15.
__global__ __launch_bounds__(512) void vq_main(
    const float* __restrict__ z, const float4* __restrict__ w4,
    const float* __restrict__ wsq1, const long* __restrict__ w2b,
    float* __restrict__ out, float* __restrict__ partials)
{
    __shared__ long lds64[NEMB * DIM / 8];   // 32 KiB bf8 codebook
    __shared__ float ldsw[NEMB];             // 2 KiB wsq1
    char* lds = (char*)lds64;

    const int tid = threadIdx.x;
    const int lane = tid & 63;
    const int wv = tid >> 6;   // wave 0..7
    const int g = lane >> 4;   // 0..3
    const int ln = lane & 15;

    const int rb0 = blockIdx.x * 512 + wv * 32;   // chunk-0 rows
    const int rb1 = rb0 + 256;                    // chunk-1 rows

    // ---- issue chunk-0 z loads first (latency overlaps staging) ----
    f32x4 raw[8];
#pragma unroll
    for (int rg = 0; rg < 2; ++rg) {
        const float* zr = z + (size_t)(rb0 + rg * 16 + ln) * DIM + g * 8;
        raw[rg * 4 + 0] = *(const f32x4*)(zr);
        raw[rg * 4 + 1] = *(const f32x4*)(zr + 4);
        raw[rg * 4 + 2] = *(const f32x4*)(zr + 32);
        raw[rg * 4 + 3] = *(const f32x4*)(zr + 36);
    }

    // ---- stage codebook (4096 8B slots, swizzled) + wsq1 ----
#pragma unroll
    for (int i = 0; i < 8; ++i) {
        int u = i * 512 + tid;
        int row = u >> 3;
        int slot = u & 7;
        long v = w2b[u];
        *(long*)(lds + row * 64 + ((slot * 8) ^ ((row & 7) << 3))) = v;
    }
    if (tid < 128) ((f32x4*)ldsw)[tid] = ((const f32x4*)wsq1)[tid];
    __syncthreads();

    // loop-invariant swizzled intra-row offsets (row&7 == ln&7 since 16|t*16)
    const int o0 = (g * 8) ^ ((ln & 7) << 3);
    const int o1 = (32 + g * 8) ^ ((ln & 7) << 3);
    const char* lrow = lds + ln * 64;
    const float* wrow = ldsw + g * 4;

    float loss_acc = 0.f;
    long zf[2][2];
    float zsq[2];

#define CVTALL                                                            \
    {                                                                     \
        _Pragma("unroll")                                                 \
        for (int rg = 0; rg < 2; ++rg) {                                  \
            float q = 0.f;                                                \
            zf[rg][0] = cvt_fp8x8(raw[rg * 4 + 0], raw[rg * 4 + 1], q);   \
            zf[rg][1] = cvt_fp8x8(raw[rg * 4 + 2], raw[rg * 4 + 3], q);   \
            q += __shfl_xor(q, 16, 64);                                   \
            q += __shfl_xor(q, 32, 64);                                   \
            zsq[rg] = q;                                                  \
        }                                                                 \
    }

#define KLOOP(BEST)                                                       \
    _Pragma("unroll")                                                     \
    for (int t = 0; t < 32; ++t) {                                        \
        long A0 = *(const long*)(lrow + t * 1024 + o0);                   \
        long A1 = *(const long*)(lrow + t * 1024 + o1);                   \
        f32x4 W = *(const f32x4*)(wrow + t * 16);                         \
        const int cb = t * 16 + g * 4;                                    \
        _Pragma("unroll")                                                 \
        for (int rg = 0; rg < 2; ++rg) {                                  \
            f32x4 acc = __builtin_amdgcn_mfma_f32_16x16x32_bf8_fp8(       \
                A0, zf[rg][0], W, 0, 0, 0);                               \
            acc = __builtin_amdgcn_mfma_f32_16x16x32_bf8_fp8(             \
                A1, zf[rg][1], acc, 0, 0, 0);                             \
            unsigned k0 = (__float_as_uint(acc[0]) & 0xFFFFFE00u) | (unsigned)(cb);     \
            unsigned k1 = (__float_as_uint(acc[1]) & 0xFFFFFE00u) | (unsigned)(cb + 1); \
            unsigned k2 = (__float_as_uint(acc[2]) & 0xFFFFFE00u) | (unsigned)(cb + 2); \
            unsigned k3 = (__float_as_uint(acc[3]) & 0xFFFFFE00u) | (unsigned)(cb + 3); \
            BEST[rg] = min(BEST[rg], min(min(k0, k1), min(k2, k3)));      \
        }                                                                 \
    }

    // merge 4 lane-groups, accumulate loss, gather+store 32 rows at RBH
#define EPI(RBH, BEST)                                                    \
    {                                                                     \
        _Pragma("unroll")                                                 \
        for (int rg = 0; rg < 2; ++rg) {                                  \
            unsigned b = BEST[rg];                                        \
            b = min(b, (unsigned)__shfl_xor((int)b, 16, 64));             \
            b = min(b, (unsigned)__shfl_xor((int)b, 32, 64));             \
            BEST[rg] = b;                                                 \
            loss_acc += zsq[rg] + (__uint_as_float(b & 0xFFFFFE00u) - 1.0f); \
        }                                                                 \
        float4* o4 = reinterpret_cast<float4*>(out);                      \
        _Pragma("unroll")                                                 \
        for (int rg = 0; rg < 2; ++rg) {                                  \
            const int base = ((RBH) + rg * 16) * 16;                      \
            _Pragma("unroll")                                             \
            for (int j = 0; j < 4; ++j) {                                 \
                int srow = 4 * j + g;                                     \
                unsigned key = (unsigned)__shfl((int)BEST[rg], srow, 64); \
                int i0 = (int)(key & 511u);                               \
                o4[base + 64 * j + lane] = ((const float4*)w4)[i0 * 16 + ln]; \
            }                                                             \
        }                                                                 \
    }

    // ===== chunk 0 =====
    CVTALL;   // waits chunk-0 z

    // issue chunk-1 z loads — stream under KLOOP0/EPI0
#pragma unroll
    for (int rg = 0; rg < 2; ++rg) {
        const float* zr = z + (size_t)(rb1 + rg * 16 + ln) * DIM + g * 8;
        raw[rg * 4 + 0] = *(const f32x4*)(zr);
        raw[rg * 4 + 1] = *(const f32x4*)(zr + 4);
        raw[rg * 4 + 2] = *(const f32x4*)(zr + 32);
        raw[rg * 4 + 3] = *(const f32x4*)(zr + 36);
    }

    {
        unsigned best[2] = { 0xFFFFFFFFu, 0xFFFFFFFFu };
        KLOOP(best);
        EPI(rb0, best);
    }

    // ===== chunk 1 =====
    CVTALL;   // z1 landed under KLOOP0
    {
        unsigned best[2] = { 0xFFFFFFFFu, 0xFFFFFFFFu };
        KLOOP(best);
        EPI(rb1, best);
    }

#undef CVTALL
#undef KLOOP
#undef EPI

#pragma unroll
    for (int m = 1; m < 64; m <<= 1) loss_acc += __shfl_xor(loss_acc, m, 64);
    if (lane == 0) partials[blockIdx.x * 8 + wv] = loss_acc;
}

// Final: reduce 4096 wave partials -> loss scalar (rows counted 4x).
__global__ __launch_bounds__(256) void vq_final(
    const float* __restrict__ partials, float* __restrict__ out)
{
    __shared__ double sh[4];
    double v = 0.0;
    for (int i = threadIdx.x; i < 4096; i += 256) v += (double)partials[i];
#pragma unroll
    for (int m = 1; m < 64; m <<= 1) v += __shfl_xor(v, m, 64);
    if ((threadIdx.x & 63) == 0) sh[threadIdx.x >> 6] = v;
    __syncthreads();
    if (threadIdx.x == 0) {
        double s = sh[0] + sh[1] + sh[2] + sh[3];
        out[(size_t)N_ROWS * DIM] =
            (float)(s * 1.1 / (4.0 * (double)N_ROWS * (double)DIM));
    }
}

extern "C" void kernel_launch(void* const* d_in, const int* in_sizes, int n_in,
                              void* d_out, int out_size, void* d_ws, size_t ws_size,
                              hipStream_t stream) {
    const float* z = (const float*)d_in[0];   // [1, 262144, 64] fp32
    const float* w = (const float*)d_in[1];   // [512, 64] fp32
    float* out = (float*)d_out;               // 262144*64 + 1 fp32

    // workspace layout (16B-aligned)
    float* partials = (float*)d_ws;                            // 4096 f32
    float* wsq1 = (float*)((char*)d_ws + 16384);               // 512 f32
    int* w2b = (int*)((char*)d_ws + 18432);                    // 512*16 ints (bf8 codebook)

    vq_prep<<<2, 256, 0, stream>>>(w, wsq1, w2b);
    vq_main<<<512, 512, 0, stream>>>(z, (const float4*)w, wsq1,
                                     (const long*)w2b, out, partials);
    vq_final<<<1, 256, 0, stream>>>(partials, out);
}

// Round 14
// 39.330 us; speedup vs baseline: 1.5842x; 1.5842x over previous
//
#include <hip/hip_runtime.h>

#define N_ROWS 262144
#define DIM 64
#define NEMB 512

typedef __attribute__((ext_vector_type(4))) float f32x4;
typedef __attribute__((ext_vector_type(2))) long i64x2;

// 8 f32 -> 8 fp8(e4m3) bytes (one i64 B-fragment), accumulating squares.
__device__ inline long cvt_fp8x8(f32x4 a, f32x4 b, float& q) {
    q = fmaf(a[0], a[0], q); q = fmaf(a[1], a[1], q);
    q = fmaf(a[2], a[2], q); q = fmaf(a[3], a[3], q);
    q = fmaf(b[0], b[0], q); q = fmaf(b[1], b[1], q);
    q = fmaf(b[2], b[2], q); q = fmaf(b[3], b[3], q);
    int lo = __builtin_amdgcn_cvt_pk_fp8_f32(a[0], a[1], 0, false);
    lo = __builtin_amdgcn_cvt_pk_fp8_f32(a[2], a[3], lo, true);
    int hi = __builtin_amdgcn_cvt_pk_fp8_f32(b[0], b[1], 0, false);
    hi = __builtin_amdgcn_cvt_pk_fp8_f32(b[2], b[3], hi, true);
    return (long)(unsigned)lo | ((long)hi << 32);
}

// Main (prep fused): 512 blocks x 512 thr (8 waves) = 2 blocks/CU, 16
// waves/CU (R12 champion shape). Per block, thread r builds codebook row r
// directly from w into LDS: bf8(e5m2) of (-2*w) in FRAGMENT-MAJOR layout
// [t][g][ln] (16B slot = A0||A1), plus wsq1 = ||w||^2 + 1. The k-loop A-load
// is then ONE ds_read_b128 per (tile,lane) — half R12's ds ops, uniform
// bank windows. e5m2 for w (|2w| <= 2^-8 < e4m3 min normal); e4m3 for z.
// Scores acc = (1+wsq) - 2 z.w via mfma_f32_16x16x32_bf8_fp8, C-in = wsq1;
// fully-unrolled k-loop (immediate ds offsets); packed-key argmin
// (9-bit idx in float LSBs); fused gather epilogue.
// C/D layout (m89): m(codeword)=4*(lane>>4)+reg, n(z-row)=lane&15.
__global__ __launch_bounds__(512) void vq_main(
    const float* __restrict__ z, const float4* __restrict__ w4,
    float* __restrict__ out, float* __restrict__ partials)
{
    __shared__ char lds[NEMB * DIM];   // 32 KiB bf8 codebook, fragment-major
    __shared__ float ldsw[NEMB];       // 2 KiB wsq1

    const int tid = threadIdx.x;
    const int lane = tid & 63;
    const int wv = tid >> 6;   // wave 0..7
    const int g = lane >> 4;   // 0..3
    const int ln = lane & 15;

    const int rb = blockIdx.x * 512 + wv * 64;

    // ---- issue all z loads first (HBM latency overlaps fused prep) ----
    f32x4 raw[16];
#pragma unroll
    for (int rg = 0; rg < 4; ++rg) {
        const float* zr = z + (size_t)(rb + rg * 16 + ln) * DIM + g * 8;
        raw[rg * 4 + 0] = *(const f32x4*)(zr);
        raw[rg * 4 + 1] = *(const f32x4*)(zr + 4);
        raw[rg * 4 + 2] = *(const f32x4*)(zr + 32);
        raw[rg * 4 + 3] = *(const f32x4*)(zr + 36);
    }

    // ---- fused prep: thread r converts codebook row r into LDS ----
    {
        const int r = tid;                       // 512 threads = 512 rows
        const float* wr = (const float*)w4 + r * DIM;
        float s = 0.f;
        int packed[16];
#pragma unroll
        for (int d4 = 0; d4 < 16; ++d4) {
            f32x4 v = *(const f32x4*)(wr + d4 * 4);
            s = fmaf(v[0], v[0], fmaf(v[1], v[1],
                fmaf(v[2], v[2], fmaf(v[3], v[3], s))));
            int p = __builtin_amdgcn_cvt_pk_bf8_f32(-2.f * v[0], -2.f * v[1], 0, false);
            p = __builtin_amdgcn_cvt_pk_bf8_f32(-2.f * v[2], -2.f * v[3], p, true);
            packed[d4] = p;
        }
        // fragment-major: slot(t=r>>4, g, ln=r&15) = bytes[8g..8g+8) || [32+8g..)
        char* base = lds + (r >> 4) * 1024 + (r & 15) * 16;
#pragma unroll
        for (int gg = 0; gg < 4; ++gg) {
            *(int4*)(base + gg * 256) =
                make_int4(packed[2 * gg], packed[2 * gg + 1],
                          packed[8 + 2 * gg], packed[8 + 2 * gg + 1]);
        }
        ldsw[r] = s + 1.0f;
    }
    __syncthreads();

    // ---- convert z -> fp8 B-frags + exact fp32 row norms ----
    long zf[4][2];
    float zsq[4];
#pragma unroll
    for (int rg = 0; rg < 4; ++rg) {
        float q = 0.f;
        zf[rg][0] = cvt_fp8x8(raw[rg * 4 + 0], raw[rg * 4 + 1], q);
        zf[rg][1] = cvt_fp8x8(raw[rg * 4 + 2], raw[rg * 4 + 3], q);
        q += __shfl_xor(q, 16, 64);
        q += __shfl_xor(q, 32, 64);
        zsq[rg] = q;                 // full ||z_row||^2, row = rb+rg*16+ln
    }

    unsigned best[4] = { 0xFFFFFFFFu, 0xFFFFFFFFu, 0xFFFFFFFFu, 0xFFFFFFFFu };

    const char* lrow = lds + g * 256 + ln * 16;   // fragment slot base
    const float* wrow = ldsw + g * 4;

    // ---- fully-unrolled k-tile loop: 32 tiles of 16 codewords ----
#pragma unroll
    for (int t = 0; t < 32; ++t) {
        i64x2 A = *(const i64x2*)(lrow + t * 1024);   // A0 || A1, one b128
        f32x4 W = *(const f32x4*)(wrow + t * 16);
        const int cb = t * 16 + g * 4;
#pragma unroll
        for (int rg = 0; rg < 4; ++rg) {
            f32x4 acc = __builtin_amdgcn_mfma_f32_16x16x32_bf8_fp8(
                A.x, zf[rg][0], W, 0, 0, 0);
            acc = __builtin_amdgcn_mfma_f32_16x16x32_bf8_fp8(
                A.y, zf[rg][1], acc, 0, 0, 0);
            unsigned k0 = (__float_as_uint(acc[0]) & 0xFFFFFE00u) | (unsigned)(cb);
            unsigned k1 = (__float_as_uint(acc[1]) & 0xFFFFFE00u) | (unsigned)(cb + 1);
            unsigned k2 = (__float_as_uint(acc[2]) & 0xFFFFFE00u) | (unsigned)(cb + 2);
            unsigned k3 = (__float_as_uint(acc[3]) & 0xFFFFFE00u) | (unsigned)(cb + 3);
            best[rg] = min(best[rg], min(min(k0, k1), min(k2, k3)));
        }
    }

    // ---- merge across the 4 lane-groups; loss + fused gather-store ----
    float loss_acc = 0.f;
#pragma unroll
    for (int rg = 0; rg < 4; ++rg) {
        unsigned b = best[rg];
        b = min(b, (unsigned)__shfl_xor((int)b, 16, 64));
        b = min(b, (unsigned)__shfl_xor((int)b, 32, 64));
        best[rg] = b;
        // key bits = bits(1 + wsq - 2 z.w) truncated; subtract the +1 bias
        loss_acc += zsq[rg] + (__uint_as_float(b & 0xFFFFFE00u) - 1.0f);
    }

    {
        float4* o4 = reinterpret_cast<float4*>(out);
#pragma unroll
        for (int rg = 0; rg < 4; ++rg) {
            const int base = (rb + rg * 16) * 16;   // f32x4 units
#pragma unroll
            for (int j = 0; j < 4; ++j) {
                int srow = 4 * j + g;               // row-in-group 0..15
                unsigned key = (unsigned)__shfl((int)best[rg], srow, 64);
                int i0 = (int)(key & 511u);
                o4[base + 64 * j + lane] = ((const float4*)w4)[i0 * 16 + ln];
            }
        }
    }

#pragma unroll
    for (int m = 1; m < 64; m <<= 1) loss_acc += __shfl_xor(loss_acc, m, 64);
    if (lane == 0) partials[blockIdx.x * 8 + wv] = loss_acc;
}

// Final: reduce 4096 wave partials -> loss scalar (rows counted 4x).
__global__ __launch_bounds__(256) void vq_final(
    const float* __restrict__ partials, float* __restrict__ out)
{
    __shared__ double sh[4];
    double v = 0.0;
    for (int i = threadIdx.x; i < 4096; i += 256) v += (double)partials[i];
#pragma unroll
    for (int m = 1; m < 64; m <<= 1) v += __shfl_xor(v, m, 64);
    if ((threadIdx.x & 63) == 0) sh[threadIdx.x >> 6] = v;
    __syncthreads();
    if (threadIdx.x == 0) {
        double s = sh[0] + sh[1] + sh[2] + sh[3];
        out[(size_t)N_ROWS * DIM] =
            (float)(s * 1.1 / (4.0 * (double)N_ROWS * (double)DIM));
    }
}

extern "C" void kernel_launch(void* const* d_in, const int* in_sizes, int n_in,
                              void* d_out, int out_size, void* d_ws, size_t ws_size,
                              hipStream_t stream) {
    const float* z = (const float*)d_in[0];   // [1, 262144, 64] fp32
    const float* w = (const float*)d_in[1];   // [512, 64] fp32
    float* out = (float*)d_out;               // 262144*64 + 1 fp32

    float* partials = (float*)d_ws;           // 4096 f32

    vq_main<<<512, 512, 0, stream>>>(z, (const float4*)w, out, partials);
    vq_final<<<1, 256, 0, stream>>>(partials, out);
}